// Round 10
// baseline (130.663 us; speedup 1.0000x reference)
//
#include <hip/hip_runtime.h>
#include <hip/hip_bf16.h>

#define N_TOKENS   262144
#define DIM        64
#define KCODES     512
#define OUT_ELEMS  (N_TOKENS * DIM)          // 16777216
#define LOSS_SCALE (1.25f / 16777216.0f)

typedef float  f32x4 __attribute__((ext_vector_type(4)));
typedef float  f32x8 __attribute__((ext_vector_type(8)));
typedef int    i32x2 __attribute__((ext_vector_type(2)));

// Pack 8 f32 -> 8 fp8 e4m3 bytes (j-th byte = fp8(v[j])) via v_cvt_pk_fp8_f32.
static __device__ __forceinline__ long pack_fp8x8(const f32x8 v) {
    int lo = __builtin_amdgcn_cvt_pk_fp8_f32(v[0], v[1], 0, false);
    lo     = __builtin_amdgcn_cvt_pk_fp8_f32(v[2], v[3], lo, true);
    int hi = __builtin_amdgcn_cvt_pk_fp8_f32(v[4], v[5], 0, false);
    hi     = __builtin_amdgcn_cvt_pk_fp8_f32(v[6], v[7], hi, true);
    i32x2 r = {lo, hi};
    return __builtin_bit_cast(long, r);
}

// Prep: codebook -> fp8(-256*c) in MFMA-fragment order (ws); c2 = 128*||c||^2+256;
// zero loss slot. Fragment byte index for (code k, dim d):
//   t=k>>4, li=k&15, kk=d>>5, hi=(d>>3)&3, j=d&7 -> ((t*2+kk)*64 + hi*16+li)*8 + j
// Scale 2^7 lifts |2c|<=1/256 out of the e4m3 subnormal floor. Uniform positive
// scale preserves the argmin; +256 bias keeps keys strictly positive so
// uint compare == float compare.
__global__ void vq_prep(const float* __restrict__ cb,
                        unsigned char* __restrict__ cbf,
                        float* __restrict__ c2,
                        float* __restrict__ out_loss) {
    const int k = blockIdx.x;       // 512 blocks, one code each
    const int d = threadIdx.x;      // 64 threads (one wave)
    const float v = cb[k * DIM + d];
    float s = v * v;
    #pragma unroll
    for (int sh = 1; sh < 64; sh <<= 1) s += __shfl_xor(s, sh, 64);
    if (d == 0) c2[k] = 128.0f * s + 256.0f;

    const int t = k >> 4, li = k & 15;
    const int kk = d >> 5, hi = (d >> 3) & 3, j = d & 7;
    const int slot = (t * 2 + kk) * 64 + hi * 16 + li;
    const int p = __builtin_amdgcn_cvt_pk_fp8_f32(-256.0f * v, 0.0f, 0, false);
    cbf[slot * 8 + j] = (unsigned char)(p & 0xFF);

    if (k == 0 && d == 0) *out_loss = 0.0f;
}

// Main: 2048 blocks x 256 threads (4 waves), 32 tokens/wave -> 8192 waves.
// NO LDS codebook (fp8 B-fragments stream from L2, ~268 MB aggregate at
// ~35 TB/s), NO __syncthreads anywhere, natural register allocation
// (~48-60 VGPR -> 8 waves/SIMD = 32 waves/CU). Latency hiding comes purely
// from TLP across decorrelated small blocks.
// NOTE: forcing min-waves>=8 in launch_bounds spilled in R3/R6 -> plain (256).
__global__ __launch_bounds__(256) void vq_main(
    const float* __restrict__ z,
    const float* __restrict__ cb,              // fp32 codebook (exact gather)
    const unsigned char* __restrict__ cbf,     // fp8(-256c), fragment order
    const float* __restrict__ c2g,             // 128*||c||^2 + 256
    float* __restrict__ out)
{
    __shared__ int keysl[4][32];               // wave-private slabs, 512 B

    const int tid  = threadIdx.x;
    const int wave = tid >> 6;
    const int lane = tid & 63;
    const int li   = lane & 15;   // A-row / C-col lane index
    const int hi   = lane >> 4;   // k-group

    const int token0 = blockIdx.x * 128 + wave * 32;

    // ---- z loads (HBM) issue first; conversion overlaps their latency ----
    const float* zb = z + (size_t)token0 * DIM + li * DIM + hi * 8;
    const f32x8 v00 = *(const f32x8*)(zb);               // m=0, k 0..31 slice
    const f32x8 v01 = *(const f32x8*)(zb + 32);          // m=0, k 32..63
    const f32x8 v10 = *(const f32x8*)(zb + 16 * DIM);    // m=1
    const f32x8 v11 = *(const f32x8*)(zb + 16 * DIM + 32);

    // ---- convert z -> fp8 A-fragments + exact fp32 ||z||^2 ----
    long af[2][2];
    float z2[2];
    {
        float zs = 0.f;
        #pragma unroll
        for (int j = 0; j < 8; ++j) zs += v00[j] * v00[j] + v01[j] * v01[j];
        af[0][0] = pack_fp8x8(v00);
        af[0][1] = pack_fp8x8(v01);
        zs += __shfl_xor(zs, 16, 64);
        zs += __shfl_xor(zs, 32, 64);
        z2[0] = zs;
    }
    {
        float zs = 0.f;
        #pragma unroll
        for (int j = 0; j < 8; ++j) zs += v10[j] * v10[j] + v11[j] * v11[j];
        af[1][0] = pack_fp8x8(v10);
        af[1][1] = pack_fp8x8(v11);
        zs += __shfl_xor(zs, 16, 64);
        zs += __shfl_xor(zs, 32, 64);
        z2[1] = zs;
    }

    // ---- argmin over 512 codes; fp8 B-fragments streamed from L2 ----
    unsigned bkey[2][4];
    #pragma unroll
    for (int m = 0; m < 2; ++m)
        #pragma unroll
        for (int r = 0; r < 4; ++r) bkey[m][r] = 0xFFFFFFFFu;

    #pragma unroll 4
    for (int t = 0; t < 32; ++t) {
        const long b0 = *(const long*)(cbf + ((size_t)(t * 2 + 0) * 64 + lane) * 8);
        const long b1 = *(const long*)(cbf + ((size_t)(t * 2 + 1) * 64 + lane) * 8);
        const float cv = c2g[t * 16 + li];
        const unsigned code = (unsigned)(t * 16 + li);
        #pragma unroll
        for (int m = 0; m < 2; ++m) {
            f32x4 acc = {cv, cv, cv, cv};
            acc = __builtin_amdgcn_mfma_f32_16x16x32_fp8_fp8(af[m][0], b0, acc, 0, 0, 0);
            acc = __builtin_amdgcn_mfma_f32_16x16x32_fp8_fp8(af[m][1], b1, acc, 0, 0, 0);
            // acc[r] = 128*(||c||^2 - 2 z.c) + 256 for row (m*16+hi*4+r), col code
            #pragma unroll
            for (int r = 0; r < 4; ++r) {
                const unsigned key = (__builtin_bit_cast(unsigned, acc[r]) & ~511u) | code;
                if (key < bkey[m][r]) bkey[m][r] = key;   // v_and_or + v_min_u32
            }
        }
    }

    // ---- reduce across the 16 li-lanes (positive-float keys: uint min) ----
    #pragma unroll
    for (int sh = 1; sh < 16; sh <<= 1) {
        #pragma unroll
        for (int m = 0; m < 2; ++m)
            #pragma unroll
            for (int r = 0; r < 4; ++r) {
                const unsigned ok = (unsigned)__shfl_xor((int)bkey[m][r], sh, 64);
                if (ok < bkey[m][r]) bkey[m][r] = ok;
            }
    }

    // rows m*16 + hi*4 + r -> key; wave-private slab (same-wave LDS ordering
    // is guaranteed by lgkmcnt, no barrier needed)
    if (li == 0) {
        #pragma unroll
        for (int m = 0; m < 2; ++m)
            #pragma unroll
            for (int r = 0; r < 4; ++r)
                keysl[wave][m * 16 + hi * 4 + r] = (int)bkey[m][r];
    }

    // ---- gather exact fp32 rows (L2-hit), write z_q, loss from key ----
    float lossp = 0.f;
    #pragma unroll
    for (int m = 0; m < 2; ++m) {
        const unsigned key = (unsigned)keysl[wave][m * 16 + li];  // row = m*16+li
        const int code = (int)(key & 511u);
        if (hi == 0) {
            const float kf = __builtin_bit_cast(float, key & ~511u);
            // dist~ = (kf - 256)/128 ; token loss = dist~ + ||z||^2
            lossp += __builtin_fmaf(kf - 256.0f, 0.0078125f, z2[m]);
        }
        const float* cbr = cb + code * DIM + hi * 8;
        const f32x8 q0 = *(const f32x8*)(cbr);
        const f32x8 q1 = *(const f32x8*)(cbr + 32);
        float* op = out + (size_t)(token0 + m * 16 + li) * DIM + hi * 8;
        *(f32x8*)(op)      = q0;
        *(f32x8*)(op + 32) = q1;
    }

    // ---- loss: wave shuffle reduce -> one atomic per wave (no barrier) ----
    #pragma unroll
    for (int sh = 1; sh < 64; sh <<= 1) lossp += __shfl_xor(lossp, sh, 64);
    if (lane == 0) atomicAdd(out + OUT_ELEMS, lossp * LOSS_SCALE);
}

extern "C" void kernel_launch(void* const* d_in, const int* in_sizes, int n_in,
                              void* d_out, int out_size, void* d_ws, size_t ws_size,
                              hipStream_t stream) {
    const float* z  = (const float*)d_in[0];
    const float* cb = (const float*)d_in[1];
    float* out = (float*)d_out;

    unsigned char* cbf = (unsigned char*)d_ws;                       // 32 KiB
    float* c2 = (float*)((char*)d_ws + KCODES * DIM);                // 2 KiB

    vq_prep<<<KCODES, 64, 0, stream>>>(cb, cbf, c2, out + OUT_ELEMS);
    vq_main<<<N_TOKENS / 128, 256, 0, stream>>>(z, cb, cbf, c2, out);
}

// Round 11
// 124.319 us; speedup vs baseline: 1.0510x; 1.0510x over previous
//
#include <hip/hip_runtime.h>
#include <hip/hip_bf16.h>

#define N_TOKENS   262144
#define DIM        64
#define KCODES     512
#define OUT_ELEMS  (N_TOKENS * DIM)          // 16777216
#define LOSS_SCALE (1.25f / 16777216.0f)

typedef float  f32x4 __attribute__((ext_vector_type(4)));
typedef float  f32x8 __attribute__((ext_vector_type(8)));
typedef int    i32x4 __attribute__((ext_vector_type(4)));
typedef int    i32x2 __attribute__((ext_vector_type(2)));

// Pack 8 f32 -> 8 fp8 e4m3 bytes (j-th byte = fp8(v[j])) via v_cvt_pk_fp8_f32.
static __device__ __forceinline__ long pack_fp8x8(const f32x8 v) {
    int lo = __builtin_amdgcn_cvt_pk_fp8_f32(v[0], v[1], 0, false);
    lo     = __builtin_amdgcn_cvt_pk_fp8_f32(v[2], v[3], lo, true);
    int hi = __builtin_amdgcn_cvt_pk_fp8_f32(v[4], v[5], 0, false);
    hi     = __builtin_amdgcn_cvt_pk_fp8_f32(v[6], v[7], hi, true);
    i32x2 r = {lo, hi};
    return __builtin_bit_cast(long, r);
}

// Prep: codebook -> fp8(-256*c) in MFMA-fragment order (ws); c2 = 128*||c||^2+256;
// zero loss slot. Fragment byte index for (code k, dim d):
//   t=k>>4, li=k&15, kk=d>>5, hi=(d>>3)&3, j=d&7 -> ((t*2+kk)*64 + hi*16+li)*8 + j
// Scale 2^7 lifts |2c|<=1/256 out of the e4m3 subnormal floor. Uniform positive
// scale preserves the argmin; +256 bias keeps keys strictly positive so
// uint compare == float compare.
__global__ void vq_prep(const float* __restrict__ cb,
                        unsigned char* __restrict__ cbf,
                        float* __restrict__ c2,
                        float* __restrict__ out_loss) {
    const int k = blockIdx.x;       // 512 blocks, one code each
    const int d = threadIdx.x;      // 64 threads (one wave)
    const float v = cb[k * DIM + d];
    float s = v * v;
    #pragma unroll
    for (int sh = 1; sh < 64; sh <<= 1) s += __shfl_xor(s, sh, 64);
    if (d == 0) c2[k] = 128.0f * s + 256.0f;

    const int t = k >> 4, li = k & 15;
    const int kk = d >> 5, hi = (d >> 3) & 3, j = d & 7;
    const int slot = (t * 2 + kk) * 64 + hi * 16 + li;
    const int p = __builtin_amdgcn_cvt_pk_fp8_f32(-256.0f * v, 0.0f, 0, false);
    cbf[slot * 8 + j] = (unsigned char)(p & 0xFF);

    if (k == 0 && d == 0) *out_loss = 0.0f;
}

// Main: 1024 blocks x 512 threads (8 waves), 32 tokens/wave = 256 tokens/block.
// fp8 codebook in LDS (32 KiB; ~36 KiB total) -> 4 blocks/CU x 8 waves
// = 32 waves/CU IF VGPR <= 64 (R10 measured 48 for this loop w/o staging).
// Plain launch_bounds(512): natural allocation (forced min-waves spilled in
// R3/R6; L2-streaming without LDS collapsed in R10 on same-line L2 service).
// One barrier total; loss via one atomic per wave.
__global__ __launch_bounds__(512) void vq_main(
    const float* __restrict__ z,
    const float* __restrict__ cb,              // fp32 codebook (exact gather)
    const unsigned char* __restrict__ cbf,     // fp8(-256c), fragment order
    const float* __restrict__ c2g,             // 128*||c||^2 + 256
    float* __restrict__ out)
{
    __shared__ unsigned char cbs[KCODES * DIM];   // 32 KiB, fragment order
    __shared__ float c2s[KCODES];                 // 2 KiB
    __shared__ int   keysl[8][32];                // 1 KiB

    const int tid  = threadIdx.x;
    const int wave = tid >> 6;
    const int lane = tid & 63;
    const int li   = lane & 15;   // A-row / C-col lane index
    const int hi   = lane >> 4;   // k-group

    const int token0 = blockIdx.x * 256 + wave * 32;

    // ---- z loads (HBM) issue first; staging + convert overlap their latency ----
    const float* zb = z + (size_t)token0 * DIM + li * DIM + hi * 8;
    const f32x8 v00 = *(const f32x8*)(zb);               // m=0, k 0..31 slice
    const f32x8 v01 = *(const f32x8*)(zb + 32);          // m=0, k 32..63
    const f32x8 v10 = *(const f32x8*)(zb + 16 * DIM);    // m=1
    const f32x8 v11 = *(const f32x8*)(zb + 16 * DIM + 32);

    // ---- stage fp8 codebook (linear, conflict-free) + c2 into LDS ----
    #pragma unroll
    for (int i = 0; i < 4; ++i)
        ((i32x4*)cbs)[i * 512 + tid] = ((const i32x4*)cbf)[i * 512 + tid];
    c2s[tid] = c2g[tid];   // tid < 512 == KCODES

    // ---- convert z -> fp8 A-fragments + exact fp32 ||z||^2 (immediate consume) ----
    long af[2][2];
    float z2[2];
    {
        float zs = 0.f;
        #pragma unroll
        for (int j = 0; j < 8; ++j) zs += v00[j] * v00[j];
        af[0][0] = pack_fp8x8(v00);
        #pragma unroll
        for (int j = 0; j < 8; ++j) zs += v01[j] * v01[j];
        af[0][1] = pack_fp8x8(v01);
        zs += __shfl_xor(zs, 16, 64);
        zs += __shfl_xor(zs, 32, 64);
        z2[0] = zs;
    }
    {
        float zs = 0.f;
        #pragma unroll
        for (int j = 0; j < 8; ++j) zs += v10[j] * v10[j];
        af[1][0] = pack_fp8x8(v10);
        #pragma unroll
        for (int j = 0; j < 8; ++j) zs += v11[j] * v11[j];
        af[1][1] = pack_fp8x8(v11);
        zs += __shfl_xor(zs, 16, 64);
        zs += __shfl_xor(zs, 32, 64);
        z2[1] = zs;
    }
    __syncthreads();   // staging complete (the only block-wide barrier)

    // ---- argmin over 512 codes; fp8 B-fragments from LDS (b64 reads) ----
    unsigned bkey[2][4];
    #pragma unroll
    for (int m = 0; m < 2; ++m)
        #pragma unroll
        for (int r = 0; r < 4; ++r) bkey[m][r] = 0xFFFFFFFFu;

    #pragma unroll 4
    for (int t = 0; t < 32; ++t) {
        const long b0 = *(const long*)&cbs[((t * 2 + 0) * 64 + lane) * 8];
        const long b1 = *(const long*)&cbs[((t * 2 + 1) * 64 + lane) * 8];
        const float cv = c2s[t * 16 + li];
        const unsigned code = (unsigned)(t * 16 + li);
        #pragma unroll
        for (int m = 0; m < 2; ++m) {
            f32x4 acc = {cv, cv, cv, cv};
            acc = __builtin_amdgcn_mfma_f32_16x16x32_fp8_fp8(af[m][0], b0, acc, 0, 0, 0);
            acc = __builtin_amdgcn_mfma_f32_16x16x32_fp8_fp8(af[m][1], b1, acc, 0, 0, 0);
            // acc[r] = 128*(||c||^2 - 2 z.c) + 256 for row (m*16+hi*4+r), col code
            #pragma unroll
            for (int r = 0; r < 4; ++r) {
                const unsigned key = (__builtin_bit_cast(unsigned, acc[r]) & ~511u) | code;
                if (key < bkey[m][r]) bkey[m][r] = key;   // v_and_or + v_min_u32
            }
        }
    }

    // ---- reduce across the 16 li-lanes (positive-float keys: uint min) ----
    #pragma unroll
    for (int sh = 1; sh < 16; sh <<= 1) {
        #pragma unroll
        for (int m = 0; m < 2; ++m)
            #pragma unroll
            for (int r = 0; r < 4; ++r) {
                const unsigned ok = (unsigned)__shfl_xor((int)bkey[m][r], sh, 64);
                if (ok < bkey[m][r]) bkey[m][r] = ok;
            }
    }

    // rows m*16 + hi*4 + r -> key; wave-private slab (same-wave LDS ordering
    // via lgkmcnt, no barrier needed)
    if (li == 0) {
        #pragma unroll
        for (int m = 0; m < 2; ++m)
            #pragma unroll
            for (int r = 0; r < 4; ++r)
                keysl[wave][m * 16 + hi * 4 + r] = (int)bkey[m][r];
    }

    // ---- gather exact fp32 rows (L2-hit), write z_q (nontemporal), loss ----
    float lossp = 0.f;
    #pragma unroll
    for (int m = 0; m < 2; ++m) {
        const unsigned key = (unsigned)keysl[wave][m * 16 + li];  // row = m*16+li
        const int code = (int)(key & 511u);
        if (hi == 0) {
            const float kf = __builtin_bit_cast(float, key & ~511u);
            // dist~ = (kf - 256)/128 ; token loss = dist~ + ||z||^2
            lossp += __builtin_fmaf(kf - 256.0f, 0.0078125f, z2[m]);
        }
        const float* cbr = cb + code * DIM + hi * 8;
        const f32x8 q0 = *(const f32x8*)(cbr);
        const f32x8 q1 = *(const f32x8*)(cbr + 32);
        float* op = out + (size_t)(token0 + m * 16 + li) * DIM + hi * 8;
        __builtin_nontemporal_store(q0, (f32x8*)(op));
        __builtin_nontemporal_store(q1, (f32x8*)(op + 32));
    }

    // ---- loss: wave shuffle reduce -> one atomic per wave (no barrier) ----
    #pragma unroll
    for (int sh = 1; sh < 64; sh <<= 1) lossp += __shfl_xor(lossp, sh, 64);
    if (lane == 0) atomicAdd(out + OUT_ELEMS, lossp * LOSS_SCALE);
}

extern "C" void kernel_launch(void* const* d_in, const int* in_sizes, int n_in,
                              void* d_out, int out_size, void* d_ws, size_t ws_size,
                              hipStream_t stream) {
    const float* z  = (const float*)d_in[0];
    const float* cb = (const float*)d_in[1];
    float* out = (float*)d_out;

    unsigned char* cbf = (unsigned char*)d_ws;                       // 32 KiB
    float* c2 = (float*)((char*)d_ws + KCODES * DIM);                // 2 KiB

    vq_prep<<<KCODES, 64, 0, stream>>>(cb, cbf, c2, out + OUT_ELEMS);
    vq_main<<<N_TOKENS / 256, 512, 0, stream>>>(z, cb, cbf, c2, out);
}

// Round 12
// 44.121 us; speedup vs baseline: 2.9615x; 2.8177x over previous
//
#include <hip/hip_runtime.h>
#include <hip/hip_bf16.h>

#define N_TOKENS   262144
#define DIM        64
#define KCODES     512
#define OUT_ELEMS  (N_TOKENS * DIM)          // 16777216
#define LOSS_SCALE (1.25f / 16777216.0f)

typedef float  f32x4 __attribute__((ext_vector_type(4)));
typedef float  f32x8 __attribute__((ext_vector_type(8)));
typedef int    i32x4 __attribute__((ext_vector_type(4)));
typedef int    i32x2 __attribute__((ext_vector_type(2)));

// Pack 8 f32 -> 8 fp8 e4m3 bytes (j-th byte = fp8(v[j])) via v_cvt_pk_fp8_f32.
static __device__ __forceinline__ long pack_fp8x8(const f32x8 v) {
    int lo = __builtin_amdgcn_cvt_pk_fp8_f32(v[0], v[1], 0, false);
    lo     = __builtin_amdgcn_cvt_pk_fp8_f32(v[2], v[3], lo, true);
    int hi = __builtin_amdgcn_cvt_pk_fp8_f32(v[4], v[5], 0, false);
    hi     = __builtin_amdgcn_cvt_pk_fp8_f32(v[6], v[7], hi, true);
    i32x2 r = {lo, hi};
    return __builtin_bit_cast(long, r);
}

// Prep: codebook -> fp8(-256*c) in MFMA-fragment order (ws); c2 = 128*||c||^2+256;
// zero loss slot. Fragment byte index for (code k, dim d):
//   t=k>>4, li=k&15, kk=d>>5, hi=(d>>3)&3, j=d&7 -> ((t*2+kk)*64 + hi*16+li)*8 + j
// Scale 2^7 lifts |2c|<=1/256 out of the e4m3 subnormal floor. Uniform positive
// scale preserves the argmin; +256 bias keeps keys strictly positive so
// uint compare == float compare.
__global__ void vq_prep(const float* __restrict__ cb,
                        unsigned char* __restrict__ cbf,
                        float* __restrict__ c2,
                        float* __restrict__ out_loss) {
    const int k = blockIdx.x;       // 512 blocks, one code each
    const int d = threadIdx.x;      // 64 threads (one wave)
    const float v = cb[k * DIM + d];
    float s = v * v;
    #pragma unroll
    for (int sh = 1; sh < 64; sh <<= 1) s += __shfl_xor(s, sh, 64);
    if (d == 0) c2[k] = 128.0f * s + 256.0f;

    const int t = k >> 4, li = k & 15;
    const int kk = d >> 5, hi = (d >> 3) & 3, j = d & 7;
    const int slot = (t * 2 + kk) * 64 + hi * 16 + li;
    const int p = __builtin_amdgcn_cvt_pk_fp8_f32(-256.0f * v, 0.0f, 0, false);
    cbf[slot * 8 + j] = (unsigned char)(p & 0xFF);

    if (k == 0 && d == 0) *out_loss = 0.0f;
}

// Main: 1024 blocks x 256 threads (4 waves); each wave pipelines TWO 32-token
// tiles: z(T1) loads are issued right after the staging barrier and stay in
// flight under T0's convert+argmin (~2500 cy) -- intra-wave memory/compute
// overlap instead of phase-locked bursts. fp8 codebook LDS = ~35 KiB ->
// 4 blocks/CU (144 KiB LDS, 1024 thr) = 16 waves/CU at VGPR<=128.
// launch_bounds(256,4): the ONLY proven-safe allocator pin (R3/R6/R11:
// anything tighter or unspecified -> 32-VGPR squeeze + scratch spill).
__global__ __launch_bounds__(256, 4) void vq_main(
    const float* __restrict__ z,
    const float* __restrict__ cb,              // fp32 codebook (exact gather)
    const unsigned char* __restrict__ cbf,     // fp8(-256c), fragment order
    const float* __restrict__ c2g,             // 128*||c||^2 + 256
    float* __restrict__ out)
{
    __shared__ unsigned char cbs[KCODES * DIM];   // 32 KiB, fragment order
    __shared__ float c2s[KCODES];                 // 2 KiB
    __shared__ int   keysl[4][32];                // 512 B
    __shared__ float lpart[4];

    const int tid  = threadIdx.x;
    const int wave = tid >> 6;
    const int lane = tid & 63;
    const int li   = lane & 15;   // A-row / C-col lane index
    const int hi   = lane >> 4;   // k-group

    // 8 wave-tiles per block: wave w owns tiles {w*2, w*2+1}
    const int   tile0  = blockIdx.x * 8 + wave * 2;
    const float* zb0 = z + (size_t)tile0 * 32 * DIM + li * DIM + hi * 8;

    // ---- tile-0 z loads issue first ----
    const f32x8 c00 = *(const f32x8*)(zb0);
    const f32x8 c01 = *(const f32x8*)(zb0 + 32);
    const f32x8 c10 = *(const f32x8*)(zb0 + 16 * DIM);
    const f32x8 c11 = *(const f32x8*)(zb0 + 16 * DIM + 32);

    // ---- stage fp8 codebook + c2 into LDS (linear, conflict-free) ----
    #pragma unroll
    for (int i = 0; i < 8; ++i)
        ((i32x4*)cbs)[i * 256 + tid] = ((const i32x4*)cbf)[i * 256 + tid];
    c2s[tid]       = c2g[tid];
    c2s[tid + 256] = c2g[tid + 256];
    __syncthreads();   // drains staging (and c-loads, which are needed now anyway)

    // ---- tile-1 z loads: in flight across ALL of tile-0's compute ----
    const float* zb1 = zb0 + 32 * DIM;
    const f32x8 n00 = *(const f32x8*)(zb1);
    const f32x8 n01 = *(const f32x8*)(zb1 + 32);
    const f32x8 n10 = *(const f32x8*)(zb1 + 16 * DIM);
    const f32x8 n11 = *(const f32x8*)(zb1 + 16 * DIM + 32);
    __builtin_amdgcn_sched_barrier(0);   // pin the prefetch issue point

    // ---- per-tile pipeline body ----
    auto process = [&](const f32x8& v00, const f32x8& v01,
                       const f32x8& v10, const f32x8& v11,
                       int token0) -> float {
        // convert z -> fp8 A-fragments + exact fp32 ||z||^2
        long af0k0, af0k1, af1k0, af1k1;
        float z2[2];
        {
            float zs = 0.f;
            #pragma unroll
            for (int j = 0; j < 8; ++j) zs += v00[j] * v00[j] + v01[j] * v01[j];
            af0k0 = pack_fp8x8(v00);
            af0k1 = pack_fp8x8(v01);
            zs += __shfl_xor(zs, 16, 64);
            zs += __shfl_xor(zs, 32, 64);
            z2[0] = zs;
        }
        {
            float zs = 0.f;
            #pragma unroll
            for (int j = 0; j < 8; ++j) zs += v10[j] * v10[j] + v11[j] * v11[j];
            af1k0 = pack_fp8x8(v10);
            af1k1 = pack_fp8x8(v11);
            zs += __shfl_xor(zs, 16, 64);
            zs += __shfl_xor(zs, 32, 64);
            z2[1] = zs;
        }

        // argmin over 512 codes; fp8 B-fragments from LDS
        unsigned bkey[2][4];
        #pragma unroll
        for (int m = 0; m < 2; ++m)
            #pragma unroll
            for (int r = 0; r < 4; ++r) bkey[m][r] = 0xFFFFFFFFu;

        #pragma unroll 4
        for (int t = 0; t < 32; ++t) {
            const long b0 = *(const long*)&cbs[((t * 2 + 0) * 64 + lane) * 8];
            const long b1 = *(const long*)&cbs[((t * 2 + 1) * 64 + lane) * 8];
            const float cv = c2s[t * 16 + li];
            const unsigned code = (unsigned)(t * 16 + li);
            #pragma unroll
            for (int m = 0; m < 2; ++m) {
                f32x4 acc = {cv, cv, cv, cv};
                acc = __builtin_amdgcn_mfma_f32_16x16x32_fp8_fp8(
                          m ? af1k0 : af0k0, b0, acc, 0, 0, 0);
                acc = __builtin_amdgcn_mfma_f32_16x16x32_fp8_fp8(
                          m ? af1k1 : af0k1, b1, acc, 0, 0, 0);
                // acc[r] = 128*(||c||^2 - 2 z.c) + 256, row m*16+hi*4+r, col code
                #pragma unroll
                for (int r = 0; r < 4; ++r) {
                    const unsigned key =
                        (__builtin_bit_cast(unsigned, acc[r]) & ~511u) | code;
                    if (key < bkey[m][r]) bkey[m][r] = key;  // v_and_or + v_min_u32
                }
            }
        }

        // reduce across the 16 li-lanes (positive-float keys: uint min)
        #pragma unroll
        for (int sh = 1; sh < 16; sh <<= 1) {
            #pragma unroll
            for (int m = 0; m < 2; ++m)
                #pragma unroll
                for (int r = 0; r < 4; ++r) {
                    const unsigned ok = (unsigned)__shfl_xor((int)bkey[m][r], sh, 64);
                    if (ok < bkey[m][r]) bkey[m][r] = ok;
                }
        }

        // rows m*16 + hi*4 + r -> key (wave-private slab; same-wave DS ordered)
        if (li == 0) {
            #pragma unroll
            for (int m = 0; m < 2; ++m)
                #pragma unroll
                for (int r = 0; r < 4; ++r)
                    keysl[wave][m * 16 + hi * 4 + r] = (int)bkey[m][r];
        }

        // gather exact fp32 rows (L2-hit), write z_q nontemporal, loss from key
        float lp = 0.f;
        #pragma unroll
        for (int m = 0; m < 2; ++m) {
            const unsigned key = (unsigned)keysl[wave][m * 16 + li];
            const int code = (int)(key & 511u);
            if (hi == 0) {
                const float kf = __builtin_bit_cast(float, key & ~511u);
                lp += __builtin_fmaf(kf - 256.0f, 0.0078125f, z2[m]);
            }
            const float* cbr = cb + code * DIM + hi * 8;
            const f32x8 q0 = *(const f32x8*)(cbr);
            const f32x8 q1 = *(const f32x8*)(cbr + 32);
            float* op = out + (size_t)(token0 + m * 16 + li) * DIM + hi * 8;
            __builtin_nontemporal_store(q0, (f32x8*)(op));
            __builtin_nontemporal_store(q1, (f32x8*)(op + 32));
        }
        return lp;
    };

    float lossp = 0.f;
    lossp += process(c00, c01, c10, c11, tile0 * 32);        // T=0 (T1 in flight)
    lossp += process(n00, n01, n10, n11, (tile0 + 1) * 32);  // T=1

    // ---- loss: wave shuffle -> per-wave slot -> one atomic per block ----
    #pragma unroll
    for (int sh = 1; sh < 64; sh <<= 1) lossp += __shfl_xor(lossp, sh, 64);
    if (lane == 0) lpart[wave] = lossp;
    __syncthreads();
    if (tid == 0) {
        const float s = lpart[0] + lpart[1] + lpart[2] + lpart[3];
        atomicAdd(out + OUT_ELEMS, s * LOSS_SCALE);
    }
}

extern "C" void kernel_launch(void* const* d_in, const int* in_sizes, int n_in,
                              void* d_out, int out_size, void* d_ws, size_t ws_size,
                              hipStream_t stream) {
    const float* z  = (const float*)d_in[0];
    const float* cb = (const float*)d_in[1];
    float* out = (float*)d_out;

    unsigned char* cbf = (unsigned char*)d_ws;                       // 32 KiB
    float* c2 = (float*)((char*)d_ws + KCODES * DIM);                // 2 KiB

    vq_prep<<<KCODES, 64, 0, stream>>>(cb, cbf, c2, out + OUT_ELEMS);
    vq_main<<<N_TOKENS / 256, 256, 0, stream>>>(z, cb, cbf, c2, out);
}